// Round 4
// baseline (279.539 us; speedup 1.0000x reference)
//
#include <hip/hip_runtime.h>
#include <math.h>

#define NUM_AA   21
#define OUT_DIM  387          // 1 + 21 + 21 + 64 + 42 + 42 + 196
#define SCALE    0.1f
#define EPS_C    1e-8f
#define WPB      4            // edges (waves) per block
#define NBLK     2048         // persistent blocks (8 per CU)

typedef float v4f __attribute__((ext_vector_type(4)));

// Per-lane gather roles (one edge per wave):
//   lane 0..41 : rA = src atom14 elem, rBd = dst atom14 elem, rLG = logit elem
//                (lanes 0..20 -> src logits, 21..41 -> dst logits)
//   lane 42..50: rRT = rot[src] row-major elem
//   lane 51..53: rRT = trans[src]*SCALE elem
__device__ __forceinline__ void issue_gather(
    const float* __restrict__ A, const float* __restrict__ R,
    const float* __restrict__ T, const float* __restrict__ LG,
    int src, int dst, int lane,
    float& rA, float& rBd, float& rRT, float& rLG)
{
    if (lane < 42) {
        rA  = A[(size_t)src * 42 + lane] * SCALE;
        rBd = A[(size_t)dst * 42 + lane] * SCALE;
        const int node = (lane < 21) ? src : dst;
        const int el   = (lane < 21) ? lane : lane - 21;
        rLG = LG[(size_t)node * NUM_AA + el];
    } else if (lane < 51) {
        rRT = R[(size_t)src * 9 + (lane - 42)];
    } else if (lane < 54) {
        rRT = T[(size_t)src * 3 + (lane - 51)] * SCALE;
    }
}

// first-max argmax over 21 candidate lanes via full-wave butterfly
__device__ __forceinline__ int argmax21(float myv, bool active, int myidx)
{
    float v = active ? myv : -3.4e38f;
    int ix = active ? myidx : 0x7fffffff;
    #pragma unroll
    for (int m = 32; m >= 1; m >>= 1) {
        const float ov = __shfl_xor(v, m);
        const int   oi = __shfl_xor(ix, m);
        if (ov > v || (ov == v && oi < ix)) { v = ov; ix = oi; }
    }
    return ix;
}

__global__ __launch_bounds__(256, 8) void edge_feat_kernel(
    const float* __restrict__ A,    // (N,14,3)
    const float* __restrict__ R,    // (N,3,3)
    const float* __restrict__ T,    // (N,3)
    const float* __restrict__ LG,   // (N,21)
    const int*   __restrict__ EI,   // (2,E)  [0]=dst, [1]=src
    float* __restrict__ out,        // (E,387)
    int E)
{
    __shared__ __align__(16) float rowsh[2][WPB * OUT_DIM];  // double-buffered rows

    const int wv   = threadIdx.x >> 6;
    const int lane = threadIdx.x & 63;
    const int ngroups = (E + WPB - 1) / WPB;

    int g = blockIdx.x;
    if (g >= ngroups) return;

    // ---- prologue: prefetch group g ----
    {
        const int e  = g * WPB + wv;
        const int ec = (e < E) ? e : 0;
        // fallthrough into loop with regs loaded below
        (void)ec;
    }
    int e0  = g * WPB + wv;
    int ec0 = (e0 < E) ? e0 : 0;
    int dst = EI[ec0];
    int src = EI[E + ec0];
    float rA = 0.f, rBd = 0.f, rRT = 0.f, rLG = 0.f;
    issue_gather(A, R, T, LG, src, dst, lane, rA, rBd, rRT, rLG);

    int buf = 0;
    while (g < ngroups) {
        const int gn = g + NBLK;

        // prefetch next group's edge indices early (hides under compute)
        const int en  = gn * WPB + wv;
        const int ecn = (en < E) ? en : 0;
        const int dstn = EI[ecn];
        const int srcn = EI[E + ecn];

        float* row = rowsh[buf] + wv * OUT_DIM;

        // ---- argmax one-hots ----
        const int seqS = argmax21(rLG, lane < 21, lane);
        const int seqD = argmax21(rLG, (lane >= 21) && (lane < 42), lane - 21);

        // ---- CA distance + RBF (all 64 lanes -> 64 RBF bins) ----
        {
            const float xs = __shfl(rA, 3),  ys = __shfl(rA, 4),  zs = __shfl(rA, 5);
            const float xd = __shfl(rBd, 3), yd = __shfl(rBd, 4), zd = __shfl(rBd, 5);
            const float dx = xd - xs, dy = yd - ys, dz = zd - zs;
            const float dca = sqrtf(dx * dx + dy * dy + dz * dz);
            const float mu  = (float)lane * (20.0f / 63.0f);
            const float z   = (dca - mu) * 3.2f;      // 1/sigma = 64/20
            row[43 + lane] = __expf(-z * z);
        }
        if (lane < 43) {
            float v;
            if (lane == 0)       v = 1.0f;
            else if (lane < 22)  v = (lane - 1  == seqS) ? 1.0f : 0.0f;
            else                 v = (lane - 22 == seqD) ? 1.0f : 0.0f;
            row[lane] = v;
        }

        // ---- local-frame coords: lane l<42 owns loc element l ----
        const int a3r = (lane / 3) * 3;
        const int a3  = (a3r > 39) ? 39 : a3r;   // clamp shfl sources for lanes>=42
        const int i   = lane - a3r;              // 0..2
        const float r0 = __shfl(rRT, 42 + i), r1 = __shfl(rRT, 45 + i), r2 = __shfl(rRT, 48 + i);
        const float t0 = __shfl(rRT, 51), t1 = __shfl(rRT, 52), t2 = __shfl(rRT, 53);
        const float xs0 = __shfl(rA, a3),  xs1 = __shfl(rA, a3 + 1),  xs2 = __shfl(rA, a3 + 2);
        const float xd0 = __shfl(rBd, a3), xd1 = __shfl(rBd, a3 + 1), xd2 = __shfl(rBd, a3 + 2);
        const float locS = r0 * (xs0 - t0) + r1 * (xs1 - t1) + r2 * (xs2 - t2);
        const float locD = r0 * (xd0 - t0) + r1 * (xd1 - t1) + r2 * (xd2 - t2);
        if (lane < 42) { row[107 + lane] = locS; row[149 + lane] = locD; }

        // ---- issue next group's gathers (latency hides under pair-dist + flush) ----
        float rA_n = 0.f, rBd_n = 0.f, rRT_n = 0.f, rLG_n = 0.f;
        issue_gather(A, R, T, LG, srcn, dstn, lane, rA_n, rBd_n, rRT_n, rLG_n);

        // ---- 196 pair distances via shfl from loc-owner lanes ----
        #pragma unroll
        for (int k = 0; k < 4; ++k) {
            const int p = lane + 64 * k;
            int aa = p / 14; if (aa > 13) aa = 13;
            int bb = p - aa * 14; if (bb > 13) bb = 13;
            const float s0 = __shfl(locS, 3 * aa), s1 = __shfl(locS, 3 * aa + 1), s2 = __shfl(locS, 3 * aa + 2);
            const float d0 = __shfl(locD, 3 * bb), d1 = __shfl(locD, 3 * bb + 1), d2 = __shfl(locD, 3 * bb + 2);
            const float ddx = s0 - d0 + EPS_C;
            const float ddy = s1 - d1 + EPS_C;
            const float ddz = s2 - d2 + EPS_C;
            const float vv = sqrtf(ddx * ddx + ddy * ddy + ddz * ddz);
            if (p < 196) row[191 + p] = vv;
        }

        __syncthreads();   // all rows of rowsh[buf] complete (also fences prev flush reads)

        // ---- flush block's 4 contiguous rows (6192 B) as aligned dwordx4 ----
        {
            const size_t base = (size_t)g * (WPB * OUT_DIM);
            float* ob = out + base;
            const long long remain = (long long)E * OUT_DIM - (long long)base;
            if (remain >= (long long)(WPB * OUT_DIM)) {
                const v4f* s4 = reinterpret_cast<const v4f*>(rowsh[buf]);
                v4f* o4 = reinterpret_cast<v4f*>(ob);
                int q = threadIdx.x;
                __builtin_nontemporal_store(s4[q], o4 + q);
                q += 256;
                if (q < (WPB * OUT_DIM) / 4)
                    __builtin_nontemporal_store(s4[q], o4 + q);
            } else {
                for (int q = threadIdx.x; q < (int)remain; q += 256)
                    __builtin_nontemporal_store(rowsh[buf][q], ob + q);
            }
        }

        buf ^= 1;
        g = gn;
        rA = rA_n; rBd = rBd_n; rRT = rRT_n; rLG = rLG_n;
    }
}

extern "C" void kernel_launch(void* const* d_in, const int* in_sizes, int n_in,
                              void* d_out, int out_size, void* d_ws, size_t ws_size,
                              hipStream_t stream) {
    const float* A  = (const float*)d_in[0];   // (N,14,3)
    const float* R  = (const float*)d_in[1];   // (N,3,3)
    const float* T  = (const float*)d_in[2];   // (N,3)
    const float* LG = (const float*)d_in[3];   // (N,21)
    const int*   EI = (const int*)d_in[4];     // (2,E)
    float* out = (float*)d_out;

    const int E = in_sizes[4] / 2;
    const int ngroups = (E + WPB - 1) / WPB;
    const int blocks = (ngroups < NBLK) ? ngroups : NBLK;
    edge_feat_kernel<<<blocks, 256, 0, stream>>>(A, R, T, LG, EI, out, E);
}

// Round 5
// 210.656 us; speedup vs baseline: 1.3270x; 1.3270x over previous
//
#include <hip/hip_runtime.h>
#include <math.h>

#define NUM_AA   21
#define OUT_DIM  387          // 1 + 21 + 21 + 64 + 42 + 42 + 196
#define SCALE    0.1f
#define EPS_C    1e-8f
#define WPB      4            // waves (edges) per block of 256 threads

typedef float v4f __attribute__((ext_vector_type(4)));

// One 64-lane wave per edge. Block stages its 4 complete output rows in LDS
// (contiguous 1548 floats = 6192 B, 16B-aligned), then flushes with aligned
// regular (cached) float4 stores — matches the 6.9 TB/s fill-kernel path.
__global__ __launch_bounds__(256) void edge_feat_kernel(
    const float* __restrict__ A,    // (N,14,3) decoded_atom14
    const float* __restrict__ R,    // (N,3,3)  rot
    const float* __restrict__ T,    // (N,3)    trans
    const float* __restrict__ LG,   // (N,21)   decoded_seq_logits
    const int*   __restrict__ EI,   // (2,E)    edge_index [0]=dst, [1]=src
    float* __restrict__ out,        // (E,387)
    int E)
{
    __shared__ __align__(16) float rowsh[WPB * OUT_DIM];  // 4 output rows
    __shared__ float gsh[WPB][96];                        // a14s(42) a14d(42) rotS(9) tS(3)
    __shared__ int   seqsh[WPB][2];

    const int wv   = threadIdx.x >> 6;
    const int lane = threadIdx.x & 63;
    const int e    = blockIdx.x * WPB + wv;
    const bool valid = (e < E);
    const int ec = valid ? e : 0;

    float* row  = rowsh + wv * OUT_DIM;
    float* a14s = gsh[wv];
    float* a14d = gsh[wv] + 42;
    float* rotS = gsh[wv] + 84;
    float* tS   = gsh[wv] + 93;

    const int dst = EI[ec];
    const int src = EI[E + ec];

    // ---- gather phase (each wave stages its own edge's node data) ----
    if (lane < 42) {
        a14s[lane] = A[(size_t)src * 42 + lane] * SCALE;
        a14d[lane] = A[(size_t)dst * 42 + lane] * SCALE;
    } else if (lane < 51) {
        rotS[lane - 42] = R[(size_t)src * 9 + (lane - 42)];
    } else if (lane < 54) {
        tS[lane - 51] = T[(size_t)src * 3 + (lane - 51)] * SCALE;
    } else if (lane < 56) {
        // argmax over 21 logits (first-max wins, matches jnp.argmax)
        const int node = (lane == 54) ? src : dst;
        const float* lg = LG + (size_t)node * NUM_AA;
        float best = lg[0]; int bi = 0;
        #pragma unroll
        for (int j = 1; j < NUM_AA; ++j) {
            float v = lg[j];
            if (v > best) { best = v; bi = j; }
        }
        seqsh[wv][lane - 54] = bi;
    }
    __syncthreads();

    // ---- compute phase 1: rbf (all 64 lanes), ones+one-hots, locS/locD ----
    {
        // CA (atom 1) distance in the scaled global frame
        const float dx = a14d[3] - a14s[3];
        const float dy = a14d[4] - a14s[4];
        const float dz = a14d[5] - a14s[5];
        const float dca = sqrtf(dx * dx + dy * dy + dz * dz);
        const float mu = (float)lane * (20.0f / 63.0f);
        const float z  = (dca - mu) * 3.2f;   // 1/sigma = 64/20
        row[43 + lane] = __expf(-z * z);
    }
    if (lane < 43) {
        float v;
        if (lane == 0)       v = 1.0f;
        else if (lane < 22)  v = (lane - 1  == seqsh[wv][0]) ? 1.0f : 0.0f;
        else                 v = (lane - 22 == seqsh[wv][1]) ? 1.0f : 0.0f;
        row[lane] = v;
    }
    if (lane < 42) {
        const int a = lane / 3;
        const int i = lane - a * 3;
        // local[a,i] = sum_j rot[j,i] * (x[a,j] - t[j])
        const float r0 = rotS[i], r1 = rotS[3 + i], r2 = rotS[6 + i];
        const float t0 = tS[0], t1 = tS[1], t2 = tS[2];
        row[107 + lane] = r0 * (a14s[a * 3 + 0] - t0)
                        + r1 * (a14s[a * 3 + 1] - t1)
                        + r2 * (a14s[a * 3 + 2] - t2);
        row[149 + lane] = r0 * (a14d[a * 3 + 0] - t0)
                        + r1 * (a14d[a * 3 + 1] - t1)
                        + r2 * (a14d[a * 3 + 2] - t2);
    }
    __syncthreads();

    // ---- compute phase 2: 196 pair distances ----
    #pragma unroll
    for (int k = 0; k < 4; ++k) {
        const int p = lane + k * 64;
        if (p < 196) {
            const unsigned a = (unsigned)p / 14u;
            const unsigned b = (unsigned)p - a * 14u;
            const float ddx = row[107 + a * 3 + 0] - row[149 + b * 3 + 0] + EPS_C;
            const float ddy = row[107 + a * 3 + 1] - row[149 + b * 3 + 1] + EPS_C;
            const float ddz = row[107 + a * 3 + 2] - row[149 + b * 3 + 2] + EPS_C;
            row[191 + p] = sqrtf(ddx * ddx + ddy * ddy + ddz * ddz);
        }
    }
    __syncthreads();

    // ---- flush: block's 1548 contiguous floats as 387 aligned float4 ----
    const long long base = (long long)blockIdx.x * (WPB * OUT_DIM);
    const long long EF   = (long long)E * OUT_DIM;
    float* ob = out + base;
    const long long remain = EF - base;

    if (remain >= (long long)(WPB * OUT_DIM)) {
        const v4f* s4 = reinterpret_cast<const v4f*>(rowsh);
        v4f* o4 = reinterpret_cast<v4f*>(ob);
        #pragma unroll
        for (int k = 0; k < 2; ++k) {
            const int q = threadIdx.x + k * 256;
            if (q < (WPB * OUT_DIM) / 4) {   // 387 float4s
                o4[q] = s4[q];
            }
        }
    } else if (remain > 0) {
        for (long long q = threadIdx.x; q < remain; q += 256) {
            ob[q] = rowsh[q];
        }
    }
}

extern "C" void kernel_launch(void* const* d_in, const int* in_sizes, int n_in,
                              void* d_out, int out_size, void* d_ws, size_t ws_size,
                              hipStream_t stream) {
    const float* A  = (const float*)d_in[0];   // (N,14,3)
    const float* R  = (const float*)d_in[1];   // (N,3,3)
    const float* T  = (const float*)d_in[2];   // (N,3)
    const float* LG = (const float*)d_in[3];   // (N,21)
    const int*   EI = (const int*)d_in[4];     // (2,E)
    float* out = (float*)d_out;

    const int E = in_sizes[4] / 2;
    const int blocks = (E + WPB - 1) / WPB;
    edge_feat_kernel<<<blocks, 256, 0, stream>>>(A, R, T, LG, EI, out, E);
}

// Round 6
// 156.313 us; speedup vs baseline: 1.7883x; 1.3477x over previous
//
#include <hip/hip_runtime.h>
#include <math.h>

#define NUM_AA   21
#define OUT_DIM  387          // 1 + 21 + 21 + 64 + 42 + 42 + 196
#define SCALE    0.1f
#define EPS_C    1e-8f
#define WPB      4            // waves (edges) per block of 256 threads
#define NBLK     2048         // persistent blocks (8 per CU)

typedef float v4f __attribute__((ext_vector_type(4)));

// Raw workgroup barrier that waits ONLY on LDS/SMEM ops (lgkmcnt), never
// draining in-flight global stores (which __syncthreads would: vmcnt(0)).
__device__ __forceinline__ void bar_lds() {
    __builtin_amdgcn_sched_barrier(0);
    asm volatile("s_waitcnt lgkmcnt(0)" ::: "memory");
    __builtin_amdgcn_s_barrier();
    __builtin_amdgcn_sched_barrier(0);
}

// Per-lane gather roles (one edge per wave):
//   lanes 0..41 : rA = src atom14 elem * SCALE, rBd = dst atom14 elem * SCALE
//   lanes 42..50: rRT = rot[src] elem;  lanes 51..53: rRT = trans[src]*SCALE
//   lanes 0..20 : rLG = src logit;      lanes 32..52: rLG = dst logit
__device__ __forceinline__ void issue_gather(
    const float* __restrict__ A, const float* __restrict__ R,
    const float* __restrict__ T, const float* __restrict__ LG,
    int src, int dst, int lane,
    float& rA, float& rBd, float& rRT, float& rLG)
{
    if (lane < 42) {
        rA  = A[(size_t)src * 42 + lane] * SCALE;
        rBd = A[(size_t)dst * 42 + lane] * SCALE;
    } else if (lane < 51) {
        rRT = R[(size_t)src * 9 + (lane - 42)];
    } else if (lane < 54) {
        rRT = T[(size_t)src * 3 + (lane - 51)] * SCALE;
    }
    if (lane < 21) {
        rLG = LG[(size_t)src * NUM_AA + lane];
    } else if (lane >= 32 && lane < 53) {
        rLG = LG[(size_t)dst * NUM_AA + (lane - 32)];
    }
}

__global__ __launch_bounds__(256, 8) void edge_feat_kernel(
    const float* __restrict__ A,    // (N,14,3)
    const float* __restrict__ R,    // (N,3,3)
    const float* __restrict__ T,    // (N,3)
    const float* __restrict__ LG,   // (N,21)
    const int*   __restrict__ EI,   // (2,E)  [0]=dst, [1]=src
    float* __restrict__ out,        // (E,387)
    int E)
{
    __shared__ __align__(16) float rowsh[WPB * OUT_DIM];  // 4 output rows
    __shared__ float gsh[WPB][96];   // a14s(42) a14d(42) rot(9) t(3)

    const int wv   = threadIdx.x >> 6;
    const int lane = threadIdx.x & 63;
    const int ngroups = (E + WPB - 1) / WPB;

    const int K  = (ngroups + gridDim.x - 1) / gridDim.x;
    const int g0 = blockIdx.x * K;
    const int g1 = (g0 + K < ngroups) ? g0 + K : ngroups;
    if (g0 >= ngroups) return;

    float* row  = rowsh + wv * OUT_DIM;
    float* a14s = gsh[wv];
    float* a14d = gsh[wv] + 42;
    float* rotS = gsh[wv] + 84;
    float* tS   = gsh[wv] + 93;

    // ---- prologue: gather group g0 into registers ----
    int e0  = g0 * WPB + wv;
    int ec0 = (e0 < E) ? e0 : E - 1;
    int dst = EI[ec0];
    int src = EI[E + ec0];
    float rA = 0.f, rBd = 0.f, rRT = 0.f, rLG = -3.4e38f;
    issue_gather(A, R, T, LG, src, dst, lane, rA, rBd, rRT, rLG);

    for (int g = g0; g < g1; ++g) {
        // prefetch next group's edge indices ASAP (max slack before gather issue)
        const int en  = (g + 1) * WPB + wv;
        const int ecn = (en < E) ? en : E - 1;
        const int dstn = EI[ecn];
        const int srcn = EI[E + ecn];

        // ---- dual argmax via 32-wide butterfly (register-only) ----
        // low half (lanes 0..31): src logits live in 0..20
        // high half (lanes 32..63): dst logits live in 32..52
        const bool act = (lane < 21) || (lane >= 32 && lane < 53);
        float av = act ? rLG : -3.4e38f;
        int   ai = act ? (lane & 31) : 0x7fffffff;
        #pragma unroll
        for (int m = 16; m >= 1; m >>= 1) {
            const float ov = __shfl_xor(av, m, 32);
            const int   oi = __shfl_xor(ai, m, 32);
            if (ov > av || (ov == av && oi < ai)) { av = ov; ai = oi; }
        }
        // ai: lanes<32 -> seqS, lanes>=32 -> seqD

        // ---- stage gathered regs into LDS ----
        if (lane < 42) { a14s[lane] = rA; a14d[lane] = rBd; }
        else if (lane < 54) { rotS[lane - 42] = rRT; }   // rot(9)+t(3) contiguous
        bar_lds();

        // ---- phase 1: RBF, ones/one-hots, local frames ----
        {
            const float dx = a14d[3] - a14s[3];
            const float dy = a14d[4] - a14s[4];
            const float dz = a14d[5] - a14s[5];
            const float dca = sqrtf(dx * dx + dy * dy + dz * dz);
            const float mu = (float)lane * (20.0f / 63.0f);
            const float z  = (dca - mu) * 3.2f;   // 1/sigma = 64/20
            row[43 + lane] = __expf(-z * z);
        }
        if (lane == 21) row[0] = 1.0f;
        if (lane < 21)  row[1 + lane] = (lane == ai) ? 1.0f : 0.0f;
        if (lane >= 32 && lane < 53) row[22 + (lane - 32)] = ((lane - 32) == ai) ? 1.0f : 0.0f;
        if (lane < 42) {
            const int a = lane / 3;
            const int i = lane - a * 3;
            const float r0 = rotS[i], r1 = rotS[3 + i], r2 = rotS[6 + i];
            const float t0 = tS[0], t1 = tS[1], t2 = tS[2];
            row[107 + lane] = r0 * (a14s[a * 3 + 0] - t0)
                            + r1 * (a14s[a * 3 + 1] - t1)
                            + r2 * (a14s[a * 3 + 2] - t2);
            row[149 + lane] = r0 * (a14d[a * 3 + 0] - t0)
                            + r1 * (a14d[a * 3 + 1] - t1)
                            + r2 * (a14d[a * 3 + 2] - t2);
        }
        bar_lds();

        // ---- issue next group's gathers (results consumed next iteration) ----
        float rA_n = 0.f, rBd_n = 0.f, rRT_n = 0.f, rLG_n = -3.4e38f;
        issue_gather(A, R, T, LG, srcn, dstn, lane, rA_n, rBd_n, rRT_n, rLG_n);

        // ---- phase 2: 196 pair distances ----
        #pragma unroll
        for (int k = 0; k < 4; ++k) {
            const int p = lane + k * 64;
            if (p < 196) {
                const unsigned a = (unsigned)p / 14u;
                const unsigned b = (unsigned)p - a * 14u;
                const float ddx = row[107 + a * 3 + 0] - row[149 + b * 3 + 0] + EPS_C;
                const float ddy = row[107 + a * 3 + 1] - row[149 + b * 3 + 1] + EPS_C;
                const float ddz = row[107 + a * 3 + 2] - row[149 + b * 3 + 2] + EPS_C;
                row[191 + p] = sqrtf(ddx * ddx + ddy * ddy + ddz * ddz);
            }
        }
        bar_lds();

        // ---- flush 4 contiguous rows (6192 B) with nt dwordx4 stores ----
        {
            const size_t base = (size_t)g * (WPB * OUT_DIM);
            float* ob = out + base;
            const long long remain = (long long)E * OUT_DIM - (long long)base;
            if (remain >= (long long)(WPB * OUT_DIM)) {
                const v4f* s4 = reinterpret_cast<const v4f*>(rowsh);
                v4f* o4 = reinterpret_cast<v4f*>(ob);
                int q = threadIdx.x;
                __builtin_nontemporal_store(s4[q], o4 + q);
                q += 256;
                if (q < (WPB * OUT_DIM) / 4)
                    __builtin_nontemporal_store(s4[q], o4 + q);
            } else if (remain > 0) {
                for (int q = threadIdx.x; q < (int)remain; q += 256)
                    __builtin_nontemporal_store(rowsh[q], ob + q);
            }
        }

        rA = rA_n; rBd = rBd_n; rRT = rRT_n; rLG = rLG_n;
    }
}

extern "C" void kernel_launch(void* const* d_in, const int* in_sizes, int n_in,
                              void* d_out, int out_size, void* d_ws, size_t ws_size,
                              hipStream_t stream) {
    const float* A  = (const float*)d_in[0];   // (N,14,3)
    const float* R  = (const float*)d_in[1];   // (N,3,3)
    const float* T  = (const float*)d_in[2];   // (N,3)
    const float* LG = (const float*)d_in[3];   // (N,21)
    const int*   EI = (const int*)d_in[4];     // (2,E)
    float* out = (float*)d_out;

    const int E = in_sizes[4] / 2;
    const int ngroups = (E + WPB - 1) / WPB;
    const int blocks = (ngroups < NBLK) ? ngroups : NBLK;
    edge_feat_kernel<<<blocks, 256, 0, stream>>>(A, R, T, LG, EI, out, E);
}

// Round 7
// 116.837 us; speedup vs baseline: 2.3926x; 1.3379x over previous
//
#include <hip/hip_runtime.h>
#include <math.h>

#define NUM_AA   21
#define OUT_DIM  387          // 1 + 21 + 21 + 64 + 42 + 42 + 196
#define SCALE    0.1f
#define EPS_C    1e-8f
#define WPB      4            // waves (edges) per block of 256 threads

typedef float v4f __attribute__((ext_vector_type(4)));

// ---------------- Kernel A: per-node precompute (N=10k, trivial) ------------
// S-struct (64 f, 256 B): [locS 0..41 | rot 42..50 | tS 51..53 | xcaS 54..56 | seqS 57 | pad..63]
// D-struct (64 f, 256 B): [a14d(scaled) 0..41 | xcaD 42..44 | seqD 45 | pad..63]
// ws layout: S structs at WS[0..N*64), D structs at WS[N*64..2*N*64)
__global__ __launch_bounds__(256) void node_pre_kernel(
    const float* __restrict__ A, const float* __restrict__ R,
    const float* __restrict__ T, const float* __restrict__ LG,
    float* __restrict__ WS, int N)
{
    const int n = blockIdx.x * 256 + threadIdx.x;
    if (n >= N) return;

    float a14[42];
    #pragma unroll
    for (int k = 0; k < 42; ++k) a14[k] = A[(size_t)n * 42 + k] * SCALE;
    float rot[9];
    #pragma unroll
    for (int k = 0; k < 9; ++k) rot[k] = R[(size_t)n * 9 + k];
    const float t0 = T[(size_t)n * 3 + 0] * SCALE;
    const float t1 = T[(size_t)n * 3 + 1] * SCALE;
    const float t2 = T[(size_t)n * 3 + 2] * SCALE;

    // argmax over 21 logits (first-max wins, matches jnp.argmax)
    const float* lg = LG + (size_t)n * NUM_AA;
    float best = lg[0]; int bi = 0;
    #pragma unroll
    for (int j = 1; j < NUM_AA; ++j) {
        float v = lg[j];
        if (v > best) { best = v; bi = j; }
    }

    float* S = WS + (size_t)n * 64;
    float* D = WS + (size_t)(N + n) * 64;

    // locS[a,i] = sum_j rot[j*3+i] * (a14[a*3+j] - t[j])
    #pragma unroll
    for (int a = 0; a < 14; ++a) {
        const float x0 = a14[a * 3 + 0] - t0;
        const float x1 = a14[a * 3 + 1] - t1;
        const float x2 = a14[a * 3 + 2] - t2;
        #pragma unroll
        for (int i = 0; i < 3; ++i)
            S[a * 3 + i] = rot[i] * x0 + rot[3 + i] * x1 + rot[6 + i] * x2;
    }
    #pragma unroll
    for (int k = 0; k < 9; ++k) S[42 + k] = rot[k];
    S[51] = t0; S[52] = t1; S[53] = t2;
    S[54] = a14[3]; S[55] = a14[4]; S[56] = a14[5];   // X_ca (scaled)
    S[57] = (float)bi;
    #pragma unroll
    for (int k = 58; k < 64; ++k) S[k] = 0.f;

    #pragma unroll
    for (int k = 0; k < 42; ++k) D[k] = a14[k];
    D[42] = a14[3]; D[43] = a14[4]; D[44] = a14[5];
    D[45] = (float)bi;
    #pragma unroll
    for (int k = 46; k < 64; ++k) D[k] = 0.f;
}

// ---------------- Kernel B: per-edge assembly -------------------------------
// One wave per edge; per-wave LDS struct stage (no block barriers until flush).
__global__ __launch_bounds__(256) void edge_feat_kernel(
    const int*   __restrict__ EI,   // (2,E)  [0]=dst, [1]=src
    const float* __restrict__ WS,   // packed node structs
    float* __restrict__ out,        // (E,387)
    int E, int N)
{
    __shared__ __align__(16) float rowsh[WPB * OUT_DIM];   // 4 output rows
    __shared__ __align__(16) float gsh[WPB][128];          // S(64) + D(64) per wave

    const int wv   = threadIdx.x >> 6;
    const int lane = threadIdx.x & 63;
    const int e    = blockIdx.x * WPB + wv;
    const int ec   = (e < E) ? e : E - 1;

    const int dst = EI[ec];
    const int src = EI[E + ec];

    float* row = rowsh + wv * OUT_DIM;
    float* gs  = gsh[wv];     // [0..63] = S[src], [64..127] = D[dst]

    // ---- gather: one 16B load per lane (lanes 0..31), stage to LDS ----
    if (lane < 32) {
        const float* base = (lane < 16)
            ? WS + (size_t)src * 64 + lane * 4
            : WS + (size_t)(N + dst) * 64 + (lane - 16) * 4;
        const v4f v = *reinterpret_cast<const v4f*>(base);
        *reinterpret_cast<v4f*>(&gs[lane * 4]) = v;
    }
    asm volatile("s_waitcnt lgkmcnt(0)" ::: "memory");   // intra-wave LDS RAW
    __builtin_amdgcn_sched_barrier(0);

    // ---- phase 1: RBF (all 64 lanes), ones/one-hots, loc copies ----
    {
        const float dx = gs[106] - gs[54];
        const float dy = gs[107] - gs[55];
        const float dz = gs[108] - gs[56];
        const float dca = __builtin_amdgcn_sqrtf(dx * dx + dy * dy + dz * dz);
        const float mu  = (float)lane * (20.0f / 63.0f);
        const float z   = (dca - mu) * 3.2f;   // 1/sigma = 64/20
        row[43 + lane] = __expf(-z * z);
    }
    const int seqS = (int)gs[57];
    const int seqD = (int)gs[109];
    if (lane == 21) row[0] = 1.0f;
    if (lane < 21) {
        row[1  + lane] = (lane == seqS) ? 1.0f : 0.0f;
        row[22 + lane] = (lane == seqD) ? 1.0f : 0.0f;
    }
    if (lane < 42) {
        const int a = lane / 3;
        const int i = lane - a * 3;
        // locD[a,i] = sum_j rot[j*3+i] * (a14d[a*3+j] - t[j])
        const float r0 = gs[42 + i], r1 = gs[45 + i], r2 = gs[48 + i];
        const float locD = r0 * (gs[64 + a * 3 + 0] - gs[51])
                         + r1 * (gs[64 + a * 3 + 1] - gs[52])
                         + r2 * (gs[64 + a * 3 + 2] - gs[53]);
        row[107 + lane] = gs[lane];    // locS (precomputed)
        row[149 + lane] = locD;
    }
    asm volatile("s_waitcnt lgkmcnt(0)" ::: "memory");   // row writes before reads
    __builtin_amdgcn_sched_barrier(0);

    // ---- phase 2: 196 pair distances ----
    #pragma unroll
    for (int k = 0; k < 4; ++k) {
        const int p = lane + k * 64;
        if (p < 196) {
            const unsigned a = (unsigned)p / 14u;
            const unsigned b = (unsigned)p - a * 14u;
            const float ddx = row[107 + a * 3 + 0] - row[149 + b * 3 + 0] + EPS_C;
            const float ddy = row[107 + a * 3 + 1] - row[149 + b * 3 + 1] + EPS_C;
            const float ddz = row[107 + a * 3 + 2] - row[149 + b * 3 + 2] + EPS_C;
            row[191 + p] = __builtin_amdgcn_sqrtf(ddx * ddx + ddy * ddy + ddz * ddz);
        }
    }

    // ---- block barrier (rows complete), then cooperative nt flush ----
    asm volatile("s_waitcnt lgkmcnt(0)" ::: "memory");
    __builtin_amdgcn_s_barrier();
    __builtin_amdgcn_sched_barrier(0);

    const long long base = (long long)blockIdx.x * (WPB * OUT_DIM);
    float* ob = out + base;
    const long long remain = (long long)E * OUT_DIM - base;

    if (remain >= (long long)(WPB * OUT_DIM)) {
        const v4f* s4 = reinterpret_cast<const v4f*>(rowsh);
        v4f* o4 = reinterpret_cast<v4f*>(ob);
        int q = threadIdx.x;
        __builtin_nontemporal_store(s4[q], o4 + q);
        q += 256;
        if (q < (WPB * OUT_DIM) / 4)
            __builtin_nontemporal_store(s4[q], o4 + q);
    } else if (remain > 0) {
        for (int q = threadIdx.x; q < (int)remain; q += 256)
            __builtin_nontemporal_store(rowsh[q], ob + q);
    }
}

extern "C" void kernel_launch(void* const* d_in, const int* in_sizes, int n_in,
                              void* d_out, int out_size, void* d_ws, size_t ws_size,
                              hipStream_t stream) {
    const float* A  = (const float*)d_in[0];   // (N,14,3)
    const float* R  = (const float*)d_in[1];   // (N,3,3)
    const float* T  = (const float*)d_in[2];   // (N,3)
    const float* LG = (const float*)d_in[3];   // (N,21)
    const int*   EI = (const int*)d_in[4];     // (2,E)
    float* out = (float*)d_out;
    float* WS  = (float*)d_ws;

    const int N = in_sizes[0] / 42;
    const int E = in_sizes[4] / 2;

    node_pre_kernel<<<(N + 255) / 256, 256, 0, stream>>>(A, R, T, LG, WS, N);

    const int blocks = (E + WPB - 1) / WPB;
    edge_feat_kernel<<<blocks, 256, 0, stream>>>(EI, WS, out, E, N);
}

// Round 8
// 108.684 us; speedup vs baseline: 2.5720x; 1.0750x over previous
//
#include <hip/hip_runtime.h>
#include <math.h>

#define NUM_AA   21
#define OUT_DIM  387          // 1 + 21 + 21 + 64 + 42 + 42 + 196
#define SCALE    0.1f
#define EPS_C    1e-8f
#define EPB      32           // edges per block (32*387*4 = 49536 B = 387 cache lines)
#define TPB      1024         // 16 waves; each wave handles 2 edges

typedef float v4f __attribute__((ext_vector_type(4)));

// ---------------- Kernel A: per-node precompute (N=10k, trivial) ------------
// S-struct (64 f, 256 B): [locS 0..41 | rot 42..50 | tS 51..53 | xcaS 54..56 | seqS 57 | pad..63]
// D-struct (48 f, 192 B): [a14d(scaled) 0..41 | xcaD 42..44 | seqD 45 | pad..47]
// ws layout: S structs at WS[0..N*64), D structs at WS[N*64 + n*48)
__global__ __launch_bounds__(256) void node_pre_kernel(
    const float* __restrict__ A, const float* __restrict__ R,
    const float* __restrict__ T, const float* __restrict__ LG,
    float* __restrict__ WS, int N)
{
    const int n = blockIdx.x * 256 + threadIdx.x;
    if (n >= N) return;

    float a14[42];
    #pragma unroll
    for (int k = 0; k < 42; ++k) a14[k] = A[(size_t)n * 42 + k] * SCALE;
    float rot[9];
    #pragma unroll
    for (int k = 0; k < 9; ++k) rot[k] = R[(size_t)n * 9 + k];
    const float t0 = T[(size_t)n * 3 + 0] * SCALE;
    const float t1 = T[(size_t)n * 3 + 1] * SCALE;
    const float t2 = T[(size_t)n * 3 + 2] * SCALE;

    // argmax over 21 logits (first-max wins, matches jnp.argmax)
    const float* lg = LG + (size_t)n * NUM_AA;
    float best = lg[0]; int bi = 0;
    #pragma unroll
    for (int j = 1; j < NUM_AA; ++j) {
        float v = lg[j];
        if (v > best) { best = v; bi = j; }
    }

    float* S = WS + (size_t)n * 64;
    float* D = WS + (size_t)N * 64 + (size_t)n * 48;

    // locS[a,i] = sum_j rot[j*3+i] * (a14[a*3+j] - t[j])
    #pragma unroll
    for (int a = 0; a < 14; ++a) {
        const float x0 = a14[a * 3 + 0] - t0;
        const float x1 = a14[a * 3 + 1] - t1;
        const float x2 = a14[a * 3 + 2] - t2;
        #pragma unroll
        for (int i = 0; i < 3; ++i)
            S[a * 3 + i] = rot[i] * x0 + rot[3 + i] * x1 + rot[6 + i] * x2;
    }
    #pragma unroll
    for (int k = 0; k < 9; ++k) S[42 + k] = rot[k];
    S[51] = t0; S[52] = t1; S[53] = t2;
    S[54] = a14[3]; S[55] = a14[4]; S[56] = a14[5];   // X_ca (scaled)
    S[57] = (float)bi;
    #pragma unroll
    for (int k = 58; k < 64; ++k) S[k] = 0.f;

    #pragma unroll
    for (int k = 0; k < 42; ++k) D[k] = a14[k];
    D[42] = a14[3]; D[43] = a14[4]; D[44] = a14[5];
    D[45] = (float)bi;
    D[46] = 0.f; D[47] = 0.f;
}

// ---------------- per-edge feature computation (gs: S[0..63], D[64..111]) ---
__device__ __forceinline__ void edge_phase1(const float* __restrict__ gs,
                                            float* __restrict__ row, int lane)
{
    {
        const float dx = gs[106] - gs[54];
        const float dy = gs[107] - gs[55];
        const float dz = gs[108] - gs[56];
        const float dca = __builtin_amdgcn_sqrtf(dx * dx + dy * dy + dz * dz);
        const float mu  = (float)lane * (20.0f / 63.0f);
        const float z   = (dca - mu) * 3.2f;   // 1/sigma = 64/20
        row[43 + lane] = __expf(-z * z);
    }
    const int seqS = (int)gs[57];
    const int seqD = (int)gs[109];
    if (lane == 21) row[0] = 1.0f;
    if (lane < 21) {
        row[1  + lane] = (lane == seqS) ? 1.0f : 0.0f;
        row[22 + lane] = (lane == seqD) ? 1.0f : 0.0f;
    }
    if (lane < 42) {
        const int a = lane / 3;
        const int i = lane - a * 3;
        const float r0 = gs[42 + i], r1 = gs[45 + i], r2 = gs[48 + i];
        const float locD = r0 * (gs[64 + a * 3 + 0] - gs[51])
                         + r1 * (gs[64 + a * 3 + 1] - gs[52])
                         + r2 * (gs[64 + a * 3 + 2] - gs[53]);
        row[107 + lane] = gs[lane];    // locS (precomputed)
        row[149 + lane] = locD;
    }
}

__device__ __forceinline__ void edge_phase2(float* __restrict__ row, int lane)
{
    #pragma unroll
    for (int k = 0; k < 4; ++k) {
        const int p = lane + k * 64;
        if (p < 196) {
            const unsigned a = (unsigned)p / 14u;
            const unsigned b = (unsigned)p - a * 14u;
            const float ddx = row[107 + a * 3 + 0] - row[149 + b * 3 + 0] + EPS_C;
            const float ddy = row[107 + a * 3 + 1] - row[149 + b * 3 + 1] + EPS_C;
            const float ddz = row[107 + a * 3 + 2] - row[149 + b * 3 + 2] + EPS_C;
            row[191 + p] = __builtin_amdgcn_sqrtf(ddx * ddx + ddy * ddy + ddz * ddz);
        }
    }
}

// ---------------- Kernel B: per-edge assembly -------------------------------
// 1024 threads = 16 waves; each wave owns 2 edges. Block output region is
// exactly 387 × 128 B (line-aligned). Single vmem gather instr per wave.
__global__ __launch_bounds__(1024, 2) void edge_feat_kernel(
    const int*   __restrict__ EI,   // (2,E)  [0]=dst, [1]=src
    const float* __restrict__ WS,   // packed node structs
    float* __restrict__ out,        // (E,387)
    int E, int N)
{
    __shared__ __align__(16) float rowsh[EPB * OUT_DIM];   // 49536 B
    __shared__ __align__(16) float gsh[16][224];           // 14336 B: S0 D0 S1 D1

    const int wv   = threadIdx.x >> 6;
    const int lane = threadIdx.x & 63;
    const int eb   = blockIdx.x * EPB + wv * 2;   // wave's first edge

    int dst0, src0, dst1, src1;
    if (eb + 1 < E) {
        const int2 d = *reinterpret_cast<const int2*>(EI + eb);
        const int2 s = *reinterpret_cast<const int2*>(EI + E + eb);
        dst0 = d.x; dst1 = d.y; src0 = s.x; src1 = s.y;
    } else {
        const int e0c = (eb < E) ? eb : E - 1;
        dst0 = EI[e0c]; src0 = EI[E + e0c];
        dst1 = dst0; src1 = src0;
    }

    float* row0 = rowsh + (size_t)(wv * 2) * OUT_DIM;
    float* row1 = row0 + OUT_DIM;
    float* gs   = gsh[wv];   // S0[0..63] D0[64..111] S1[112..175] D1[176..223]

    // ---- gather: lanes 0-15 S0, 16-27 D0, 28-43 S1, 44-55 D1 (16B each) ----
    {
        const int k   = (lane >= 28) ? 1 : 0;
        const int lr  = lane - k * 28;          // 0..27
        const bool isD = lr >= 16;
        const int sub = isD ? lr - 16 : lr;
        const int node = isD ? (k ? dst1 : dst0) : (k ? src1 : src0);
        const float* p = isD
            ? WS + (size_t)N * 64 + (size_t)node * 48 + sub * 4
            : WS + (size_t)node * 64 + sub * 4;
        if (lane < 56) {
            const v4f v = *reinterpret_cast<const v4f*>(p);
            *reinterpret_cast<v4f*>(&gs[k * 112 + (isD ? 64 : 0) + sub * 4]) = v;
        }
    }
    asm volatile("s_waitcnt lgkmcnt(0)" ::: "memory");
    __builtin_amdgcn_sched_barrier(0);

    // ---- phase 1 for both edges ----
    edge_phase1(gs,       row0, lane);
    edge_phase1(gs + 112, row1, lane);
    asm volatile("s_waitcnt lgkmcnt(0)" ::: "memory");
    __builtin_amdgcn_sched_barrier(0);

    // ---- phase 2 for both edges ----
    edge_phase2(row0, lane);
    edge_phase2(row1, lane);

    // ---- block barrier, then line-aligned cooperative nt flush ----
    asm volatile("s_waitcnt lgkmcnt(0)" ::: "memory");
    __builtin_amdgcn_s_barrier();
    __builtin_amdgcn_sched_barrier(0);

    const long long base = (long long)blockIdx.x * (EPB * OUT_DIM);
    float* ob = out + base;
    const long long remain = (long long)E * OUT_DIM - base;

    if (remain >= (long long)(EPB * OUT_DIM)) {
        const v4f* s4 = reinterpret_cast<const v4f*>(rowsh);
        v4f* o4 = reinterpret_cast<v4f*>(ob);
        #pragma unroll
        for (int r = 0; r < 4; ++r) {
            const int q = threadIdx.x + r * TPB;
            if (q < (EPB * OUT_DIM) / 4)   // 3096 float4s
                __builtin_nontemporal_store(s4[q], o4 + q);
        }
    } else if (remain > 0) {
        for (int q = threadIdx.x; q < (int)remain; q += TPB)
            __builtin_nontemporal_store(rowsh[q], ob + q);
    }
}

extern "C" void kernel_launch(void* const* d_in, const int* in_sizes, int n_in,
                              void* d_out, int out_size, void* d_ws, size_t ws_size,
                              hipStream_t stream) {
    const float* A  = (const float*)d_in[0];   // (N,14,3)
    const float* R  = (const float*)d_in[1];   // (N,3,3)
    const float* T  = (const float*)d_in[2];   // (N,3)
    const float* LG = (const float*)d_in[3];   // (N,21)
    const int*   EI = (const int*)d_in[4];     // (2,E)
    float* out = (float*)d_out;
    float* WS  = (float*)d_ws;

    const int N = in_sizes[0] / 42;
    const int E = in_sizes[4] / 2;

    node_pre_kernel<<<(N + 255) / 256, 256, 0, stream>>>(A, R, T, LG, WS, N);

    const int blocks = (E + EPB - 1) / EPB;
    edge_feat_kernel<<<blocks, TPB, 0, stream>>>(EI, WS, out, E, N);
}